// Round 8
// baseline (704.843 us; speedup 1.0000x reference)
//
#include <hip/hip_runtime.h>
#include <cstdint>
#include <cstddef>

#define HD   1024
#define SEQL 200
#define MEMN 50
#define RTOT 51200   // 256 * 200
#define KP   128
#define PADK 136     // KP + 8 bf16 pad -> LDS row stride 272B (2-way, free)

typedef float  f4    __attribute__((ext_vector_type(4)));
typedef float  f32x4 __attribute__((ext_vector_type(4)));
typedef short  s16x8 __attribute__((ext_vector_type(8)));
typedef unsigned short u16;
typedef unsigned short u16x4 __attribute__((ext_vector_type(4)));

__device__ __forceinline__ u16 f2bf(float f) {
    unsigned u = __builtin_bit_cast(unsigned, f);
    u += 0x7FFFu + ((u >> 16) & 1u);          // RNE
    return (u16)(u >> 16);
}
__device__ __forceinline__ float bf2f(u16 h) {
    unsigned u = ((unsigned)h) << 16;
    return __builtin_bit_cast(float, u);
}

// ---------------------------------------------------------------------------
// K0a: gate_w f32 -> bf16, layout [o][2048] k-contig. Wf = cols 0..1023,
//      Wm = cols 1024..2047.
// ---------------------------------------------------------------------------
__global__ __launch_bounds__(256) void k_cvt_w(const float* __restrict__ gw,
                                               u16* __restrict__ gwB)
{
    const size_t i = ((size_t)blockIdx.x * 256 + threadIdx.x) * 8;
    f4 v0 = *(const f4*)&gw[i];
    f4 v1 = *(const f4*)&gw[i + 4];
    u16x4 b0 = { f2bf(v0.x), f2bf(v0.y), f2bf(v0.z), f2bf(v0.w) };
    u16x4 b1 = { f2bf(v1.x), f2bf(v1.y), f2bf(v1.z), f2bf(v1.w) };
    *(u16x4*)&gwB[i]     = b0;
    *(u16x4*)&gwB[i + 4] = b1;
}

// ---------------------------------------------------------------------------
// K0b: spatial memory -> {memHi, memLo} [64][1024] bf16 (rows 50..63 zero)
//      and memT [1024][64] bf16 (hi, transposed, zero-padded).
// ---------------------------------------------------------------------------
__global__ __launch_bounds__(256) void k_prep_mem(const float* __restrict__ sm,
                                                  u16* __restrict__ memHi,
                                                  u16* __restrict__ memLo,
                                                  u16* __restrict__ memT)
{
    const int idx = blockIdx.x * 256 + threadIdx.x;   // 16384 total
    const int m  = idx >> 8;
    const int h0 = (idx & 255) * 4;
    f4 v = {0.f, 0.f, 0.f, 0.f};
    if (m < MEMN) v = *(const f4*)&sm[(size_t)m * HD + h0];
    u16x4 hi = { f2bf(v.x), f2bf(v.y), f2bf(v.z), f2bf(v.w) };
    f4 hv = { bf2f(hi.x), bf2f(hi.y), bf2f(hi.z), bf2f(hi.w) };
    f4 lv = v - hv;
    u16x4 lo = { f2bf(lv.x), f2bf(lv.y), f2bf(lv.z), f2bf(lv.w) };
    *(u16x4*)&memHi[(size_t)m * HD + h0] = hi;
    *(u16x4*)&memLo[(size_t)m * HD + h0] = lo;
    memT[(size_t)(h0 + 0) * 64 + m] = hi.x;
    memT[(size_t)(h0 + 1) * 64 + m] = hi.y;
    memT[(size_t)(h0 + 2) * 64 + m] = hi.z;
    memT[(size_t)(h0 + 3) * 64 + m] = hi.w;
}

// ---------------------------------------------------------------------------
// K0c: posM[s][m] = dot(pos[s], M[m])  f32, [200][64], zero-pad m>=50.
// ---------------------------------------------------------------------------
__global__ __launch_bounds__(256) void k_posm(const float* __restrict__ pos,
                                              const float* __restrict__ sm,
                                              float* __restrict__ posM)
{
    __shared__ float red[256];
    const int s = blockIdx.x, m = threadIdx.x & 63, ch = threadIdx.x >> 6;
    float p = 0.f;
    if (m < MEMN) {
        for (int k = ch * 256; k < ch * 256 + 256; k += 4) {
            f4 pv = *(const f4*)&pos[(size_t)s * HD + k];
            f4 mv = *(const f4*)&sm[(size_t)m * HD + k];
            p += pv.x * mv.x + pv.y * mv.y + pv.z * mv.z + pv.w * mv.w;
        }
    }
    red[threadIdx.x] = p;
    __syncthreads();
    if (ch == 0)
        posM[s * 64 + m] = red[m] + red[64 + m] + red[128 + m] + red[192 + m];
}

// ---------------------------------------------------------------------------
// K0d: MWmT[o][m] = (M @ Wm)(m,o) as bf16, [1024][64].  MFMA, 16 blocks.
// ---------------------------------------------------------------------------
__global__ __launch_bounds__(256) void k_mwm(const u16* __restrict__ memHi,
                                             const u16* __restrict__ gwB,
                                             u16* __restrict__ MWmT)
{
    const int tid = threadIdx.x, lane = tid & 63, w = tid >> 6;
    const int fr = lane & 15, fk = (lane >> 4) * 8, jr = (lane >> 4) * 4;
    const int ob = blockIdx.x * 64 + w * 16;       // o-base of this wave
    f32x4 acc[4] = {};
    for (int ks = 0; ks < 32; ++ks) {
        s16x8 b = *(const s16x8*)&gwB[(size_t)(ob + fr) * 2048 + 1024 + ks * 32 + fk];
        #pragma unroll
        for (int mt = 0; mt < 4; ++mt) {
            s16x8 a = *(const s16x8*)&memHi[(size_t)(mt * 16 + fr) * HD + ks * 32 + fk];
            acc[mt] = __builtin_amdgcn_mfma_f32_16x16x32_bf16(a, b, acc[mt], 0, 0, 0);
        }
    }
    #pragma unroll
    for (int mt = 0; mt < 4; ++mt)
        #pragma unroll
        for (int j = 0; j < 4; ++j)
            MWmT[(size_t)(ob + fr) * 64 + mt * 16 + jr + j] = f2bf(acc[mt][j]);
}

// ---------------------------------------------------------------------------
// K1: FUSED. Per block: 32 rows, 512 threads (8 waves).
//   Phase 1: stage x+pos -> feats bf16 in LDS (swizzled) + x hi/lo panels;
//            sim = x@M^T (hi/lo split MFMA, B from L2) + posM; softmax -> wBL.
//   Phase 2 (barrier-free): gate GEMM K=1024(+64): A from feats LDS / wBL,
//            B streamed from L2 (gwB / MWmT). Wave w owns cols w*128..+127.
//   Phase 3: accR = w@M (2 MFMA per subtile); out = feats + sigmoid*accR.
// ---------------------------------------------------------------------------
__global__ __launch_bounds__(512, 2) void k_fused(
    const float* __restrict__ x, const float* __restrict__ pos,
    const u16* __restrict__ memHi, const u16* __restrict__ memLo,
    const u16* __restrict__ memT, const u16* __restrict__ MWmT,
    const u16* __restrict__ gwB, const float* __restrict__ posM,
    const float* __restrict__ gb, float* __restrict__ out)
{
    __shared__ u16 featsL[32 * 1024];   // 64 KB, XOR-swizzled 16B slots
    __shared__ u16 fHi[32 * PADK];      // 8.5 KB (overlaid by simS later)
    __shared__ u16 fLo[32 * PADK];      // 8.5 KB
    __shared__ u16 wBL[32 * 80];        // 5 KB softmax weights bf16

    const int tid  = threadIdx.x;
    const int r0   = blockIdx.x * 32;
    const int lane = tid & 63, w = tid >> 6;
    const int fr = lane & 15, sg = lane >> 4;
    const int fk = sg * 8, jr = sg * 4;

    // phase-1 staging: 16 threads/row, 8 cols each per 128-panel
    const int srow = tid >> 4;
    const int scol = (tid & 15) * 8;
    const int prow = (r0 + srow) % SEQL;
    const float* xrow = &x[(size_t)(r0 + srow) * HD];
    const float* prp  = &pos[(size_t)prow * HD];

    // sim ownership: wave w -> (row-tile rt_s, m-tile nn)
    const int rt_s = w >> 2, nn = w & 3;

    f4 xa0 = *(const f4*)&xrow[scol];
    f4 xa1 = *(const f4*)&xrow[scol + 4];
    f4 pa0 = *(const f4*)&prp[scol];
    f4 pa1 = *(const f4*)&prp[scol + 4];

    f32x4 accS = {};

    for (int kp = 0; kp < HD; kp += KP) {
        // ---- convert current panel -> LDS ----
        {
            const int c0 = kp + scol;
            f4 f0 = xa0 + pa0, f1 = xa1 + pa1;
            u16x4 fb0 = { f2bf(f0.x), f2bf(f0.y), f2bf(f0.z), f2bf(f0.w) };
            u16x4 fb1 = { f2bf(f1.x), f2bf(f1.y), f2bf(f1.z), f2bf(f1.w) };
            const int slot = (c0 >> 3) ^ (srow & 7);
            u16* fp = &featsL[srow * 1024 + slot * 8];
            *(u16x4*)fp       = fb0;
            *(u16x4*)(fp + 4) = fb1;
            u16x4 h0 = { f2bf(xa0.x), f2bf(xa0.y), f2bf(xa0.z), f2bf(xa0.w) };
            u16x4 h1 = { f2bf(xa1.x), f2bf(xa1.y), f2bf(xa1.z), f2bf(xa1.w) };
            f4 hv0 = { bf2f(h0.x), bf2f(h0.y), bf2f(h0.z), bf2f(h0.w) };
            f4 hv1 = { bf2f(h1.x), bf2f(h1.y), bf2f(h1.z), bf2f(h1.w) };
            f4 l0 = xa0 - hv0, l1 = xa1 - hv1;
            u16x4 lo0 = { f2bf(l0.x), f2bf(l0.y), f2bf(l0.z), f2bf(l0.w) };
            u16x4 lo1 = { f2bf(l1.x), f2bf(l1.y), f2bf(l1.z), f2bf(l1.w) };
            *(u16x4*)&fHi[srow * PADK + scol]     = h0;
            *(u16x4*)&fHi[srow * PADK + scol + 4] = h1;
            *(u16x4*)&fLo[srow * PADK + scol]     = lo0;
            *(u16x4*)&fLo[srow * PADK + scol + 4] = lo1;
        }
        __syncthreads();

        // ---- prefetch next panel (valid addr always; unused in last iter) --
        const int kpn = (kp + KP < HD) ? kp + KP : 0;
        f4 xb0 = *(const f4*)&xrow[kpn + scol];
        f4 xb1 = *(const f4*)&xrow[kpn + scol + 4];
        f4 pb0 = *(const f4*)&prp[kpn + scol];
        f4 pb1 = *(const f4*)&prp[kpn + scol + 4];

        // ---- sim MFMA: this wave's (rt_s, nn) tile, 3 split-passes ----
        #pragma unroll
        for (int ks = 0; ks < KP / 32; ++ks) {
            const int kb = ks * 32 + fk;
            s16x8 aH = *(const s16x8*)&fHi[(rt_s * 16 + fr) * PADK + kb];
            s16x8 aL = *(const s16x8*)&fLo[(rt_s * 16 + fr) * PADK + kb];
            const size_t mb = (size_t)(nn * 16 + fr) * HD + kp + kb;
            s16x8 bH = *(const s16x8*)&memHi[mb];
            s16x8 bL = *(const s16x8*)&memLo[mb];
            accS = __builtin_amdgcn_mfma_f32_16x16x32_bf16(aH, bH, accS, 0, 0, 0);
            accS = __builtin_amdgcn_mfma_f32_16x16x32_bf16(aH, bL, accS, 0, 0, 0);
            accS = __builtin_amdgcn_mfma_f32_16x16x32_bf16(aL, bH, accS, 0, 0, 0);
        }
        __syncthreads();

        xa0 = xb0; xa1 = xb1; pa0 = pb0; pa1 = pb1;
    }

    // ---- sim -> LDS (overlay fHi), softmax, wBL ----
    float* simS = (float*)fHi;                 // [32][68] f32 (8704 B fits)
    #pragma unroll
    for (int j = 0; j < 4; ++j)
        simS[(rt_s * 16 + jr + j) * 68 + nn * 16 + fr] = accS[j];
    __syncthreads();

    {
        const int row = tid >> 4, l16 = tid & 15;
        const int rr = (r0 + row) % SEQL;
        float v[4], mx = -1e30f;
        #pragma unroll
        for (int n = 0; n < 4; ++n) {
            const int m = n * 16 + l16;
            v[n] = simS[row * 68 + m] + posM[rr * 64 + m];
            if (m < MEMN) mx = fmaxf(mx, v[n]);
        }
        #pragma unroll
        for (int d = 1; d < 16; d <<= 1) mx = fmaxf(mx, __shfl_xor(mx, d));
        float e[4], s = 0.f;
        #pragma unroll
        for (int n = 0; n < 4; ++n) {
            const int m = n * 16 + l16;
            e[n] = (m < MEMN) ? __expf(v[n] - mx) : 0.f;
            s += e[n];
        }
        #pragma unroll
        for (int d = 1; d < 16; d <<= 1) s += __shfl_xor(s, d);
        const float inv = 1.f / s;
        #pragma unroll
        for (int n = 0; n < 4; ++n)
            wBL[row * 80 + n * 16 + l16] = f2bf(e[n] * inv);   // 0 pad m>=50
    }
    __syncthreads();

    // ---- phase 2: gate GEMM, barrier-free. wave w -> cols w*128..+127 ----
    const int wc0 = w * 128;
    f32x4 acc[2][8] = {};

    #pragma unroll 2
    for (int kt = 0; kt < 32; ++kt) {
        s16x8 aF[2], bF[8];
        #pragma unroll
        for (int rt = 0; rt < 2; ++rt) {
            const int row = rt * 16 + fr;
            const int slot = (kt * 4 + sg) ^ (row & 7);
            aF[rt] = *(const s16x8*)&featsL[row * 1024 + slot * 8];
        }
        #pragma unroll
        for (int n = 0; n < 8; ++n) {
            const int col = wc0 + n * 16 + fr;
            bF[n] = *(const s16x8*)&gwB[(size_t)col * 2048 + kt * 32 + fk];
        }
        #pragma unroll
        for (int rt = 0; rt < 2; ++rt)
            #pragma unroll
            for (int n = 0; n < 8; ++n)
                acc[rt][n] = __builtin_amdgcn_mfma_f32_16x16x32_bf16(
                    aF[rt], bF[n], acc[rt][n], 0, 0, 0);
    }
    // K tail: w @ MWm (k = 0..63, zero-padded)
    #pragma unroll
    for (int ks = 0; ks < 2; ++ks) {
        s16x8 aW[2], bW[8];
        #pragma unroll
        for (int rt = 0; rt < 2; ++rt)
            aW[rt] = *(const s16x8*)&wBL[(rt * 16 + fr) * 80 + ks * 32 + fk];
        #pragma unroll
        for (int n = 0; n < 8; ++n) {
            const int col = wc0 + n * 16 + fr;
            bW[n] = *(const s16x8*)&MWmT[(size_t)col * 64 + ks * 32 + fk];
        }
        #pragma unroll
        for (int rt = 0; rt < 2; ++rt)
            #pragma unroll
            for (int n = 0; n < 8; ++n)
                acc[rt][n] = __builtin_amdgcn_mfma_f32_16x16x32_bf16(
                    aW[rt], bW[n], acc[rt][n], 0, 0, 0);
    }

    // ---- phase 3: epilogue ----
    #pragma unroll
    for (int rt = 0; rt < 2; ++rt) {
        s16x8 aW0 = *(const s16x8*)&wBL[(rt * 16 + fr) * 80 + fk];
        s16x8 aW1 = *(const s16x8*)&wBL[(rt * 16 + fr) * 80 + 32 + fk];
        #pragma unroll
        for (int n = 0; n < 8; ++n) {
            const int col = wc0 + n * 16 + fr;
            s16x8 bT0 = *(const s16x8*)&memT[(size_t)col * 64 + fk];
            s16x8 bT1 = *(const s16x8*)&memT[(size_t)col * 64 + 32 + fk];
            f32x4 aR = {};
            aR = __builtin_amdgcn_mfma_f32_16x16x32_bf16(aW0, bT0, aR, 0, 0, 0);
            aR = __builtin_amdgcn_mfma_f32_16x16x32_bf16(aW1, bT1, aR, 0, 0, 0);
            const float bias = gb[col];
            #pragma unroll
            for (int j = 0; j < 4; ++j) {
                const int row = rt * 16 + jr + j;
                const int slot = (col >> 3) ^ (row & 7);
                const float fe = bf2f(featsL[row * 1024 + slot * 8 + (col & 7)]);
                const float pre = acc[rt][n][j] + bias;
                const float g = 1.0f / (1.0f + __expf(-pre));
                out[(size_t)(r0 + row) * HD + col] = fe + g * aR[j];
            }
        }
    }
}

// ---------------------------------------------------------------------------
extern "C" void kernel_launch(void* const* d_in, const int* in_sizes, int n_in,
                              void* d_out, int out_size, void* d_ws, size_t ws_size,
                              hipStream_t stream)
{
    const float* x   = (const float*)d_in[0];
    const float* sm  = (const float*)d_in[1];
    const float* pos = (const float*)d_in[2];
    const float* gw  = (const float*)d_in[3];
    const float* gb  = (const float*)d_in[4];
    float* out = (float*)d_out;

    u16* gwB    = (u16*)d_ws;                          // 1024*2048
    u16* memHi  = gwB + (size_t)HD * 2048;             // 64*1024
    u16* memLo  = memHi + 64 * HD;                     // 64*1024
    u16* memT   = memLo + 64 * HD;                     // 1024*64
    u16* MWmT   = memT + (size_t)HD * 64;              // 1024*64
    float* posM = (float*)(MWmT + (size_t)HD * 64);    // 200*64 f32

    k_cvt_w<<<dim3(1024), dim3(256), 0, stream>>>(gw, gwB);
    k_prep_mem<<<dim3(64), dim3(256), 0, stream>>>(sm, memHi, memLo, memT);
    k_posm<<<dim3(SEQL), dim3(256), 0, stream>>>(pos, sm, posM);
    k_mwm<<<dim3(16), dim3(256), 0, stream>>>(memHi, gwB, MWmT);
    k_fused<<<dim3(RTOT / 32), dim3(512), 0, stream>>>(
        x, pos, memHi, memLo, memT, MWmT, gwB, posM, gb, out);
}

// Round 9
// 473.886 us; speedup vs baseline: 1.4874x; 1.4874x over previous
//
#include <hip/hip_runtime.h>
#include <cstdint>
#include <cstddef>

#define HD   1024
#define SEQL 200
#define MEMN 50
#define RTOT 51200   // 256 * 200
#define KP   128
#define PADK 136     // KP + 8 bf16 pad -> LDS row stride 272B (2-way, free)

typedef float  f4    __attribute__((ext_vector_type(4)));
typedef float  f32x4 __attribute__((ext_vector_type(4)));
typedef short  s16x8 __attribute__((ext_vector_type(8)));
typedef unsigned short u16;
typedef unsigned short u16x4 __attribute__((ext_vector_type(4)));
typedef unsigned short u16x8 __attribute__((ext_vector_type(8)));

__device__ __forceinline__ u16 f2bf(float f) {
    unsigned u = __builtin_bit_cast(unsigned, f);
    u += 0x7FFFu + ((u >> 16) & 1u);          // RNE
    return (u16)(u >> 16);
}
__device__ __forceinline__ float bf2f(u16 h) {
    unsigned u = ((unsigned)h) << 16;
    return __builtin_bit_cast(float, u);
}

#define GLOAD_LDS16(g, l) __builtin_amdgcn_global_load_lds( \
    (const __attribute__((address_space(1))) unsigned int*)(g), \
    (__attribute__((address_space(3))) unsigned int*)(l), 16, 0, 0)

#define WAITV4 asm volatile("s_waitcnt vmcnt(4)" ::: "memory")
#define WAITV0 asm volatile("s_waitcnt vmcnt(0)" ::: "memory")
#define LGKMFENCE asm volatile("s_waitcnt lgkmcnt(0)" ::: "memory")
#define SCHB   __builtin_amdgcn_sched_barrier(0)

// ---------------------------------------------------------------------------
// K0a: gate_w f32 -> bf16, layout [o][2048] k-contig. Wf = cols 0..1023,
//      Wm = cols 1024..2047.
// ---------------------------------------------------------------------------
__global__ __launch_bounds__(256) void k_cvt_w(const float* __restrict__ gw,
                                               u16* __restrict__ gwB)
{
    const size_t i = ((size_t)blockIdx.x * 256 + threadIdx.x) * 8;
    f4 v0 = *(const f4*)&gw[i];
    f4 v1 = *(const f4*)&gw[i + 4];
    u16x4 b0 = { f2bf(v0.x), f2bf(v0.y), f2bf(v0.z), f2bf(v0.w) };
    u16x4 b1 = { f2bf(v1.x), f2bf(v1.y), f2bf(v1.z), f2bf(v1.w) };
    *(u16x4*)&gwB[i]     = b0;
    *(u16x4*)&gwB[i + 4] = b1;
}

// ---------------------------------------------------------------------------
// K0b: spatial memory -> {memHi, memLo} [64][1024] bf16 (rows 50..63 zero)
//      and memT [1024][64] bf16 (hi, transposed, zero-padded).
// ---------------------------------------------------------------------------
__global__ __launch_bounds__(256) void k_prep_mem(const float* __restrict__ sm,
                                                  u16* __restrict__ memHi,
                                                  u16* __restrict__ memLo,
                                                  u16* __restrict__ memT)
{
    const int idx = blockIdx.x * 256 + threadIdx.x;   // 16384 total
    const int m  = idx >> 8;
    const int h0 = (idx & 255) * 4;
    f4 v = {0.f, 0.f, 0.f, 0.f};
    if (m < MEMN) v = *(const f4*)&sm[(size_t)m * HD + h0];
    u16x4 hi = { f2bf(v.x), f2bf(v.y), f2bf(v.z), f2bf(v.w) };
    f4 hv = { bf2f(hi.x), bf2f(hi.y), bf2f(hi.z), bf2f(hi.w) };
    f4 lv = v - hv;
    u16x4 lo = { f2bf(lv.x), f2bf(lv.y), f2bf(lv.z), f2bf(lv.w) };
    *(u16x4*)&memHi[(size_t)m * HD + h0] = hi;
    *(u16x4*)&memLo[(size_t)m * HD + h0] = lo;
    memT[(size_t)(h0 + 0) * 64 + m] = hi.x;
    memT[(size_t)(h0 + 1) * 64 + m] = hi.y;
    memT[(size_t)(h0 + 2) * 64 + m] = hi.z;
    memT[(size_t)(h0 + 3) * 64 + m] = hi.w;
}

// ---------------------------------------------------------------------------
// K0c: posM[s][m] = dot(pos[s], M[m])  f32, [200][64], zero-pad m>=50.
// ---------------------------------------------------------------------------
__global__ __launch_bounds__(256) void k_posm(const float* __restrict__ pos,
                                              const float* __restrict__ sm,
                                              float* __restrict__ posM)
{
    __shared__ float red[256];
    const int s = blockIdx.x, m = threadIdx.x & 63, ch = threadIdx.x >> 6;
    float p = 0.f;
    if (m < MEMN) {
        for (int k = ch * 256; k < ch * 256 + 256; k += 4) {
            f4 pv = *(const f4*)&pos[(size_t)s * HD + k];
            f4 mv = *(const f4*)&sm[(size_t)m * HD + k];
            p += pv.x * mv.x + pv.y * mv.y + pv.z * mv.z + pv.w * mv.w;
        }
    }
    red[threadIdx.x] = p;
    __syncthreads();
    if (ch == 0)
        posM[s * 64 + m] = red[m] + red[64 + m] + red[128 + m] + red[192 + m];
}

// ---------------------------------------------------------------------------
// K0d: MWmT[o][m] = (M @ Wm)(m,o) as bf16, [1024][64].  MFMA, 16 blocks.
// ---------------------------------------------------------------------------
__global__ __launch_bounds__(256) void k_mwm(const u16* __restrict__ memHi,
                                             const u16* __restrict__ gwB,
                                             u16* __restrict__ MWmT)
{
    const int tid = threadIdx.x, lane = tid & 63, w = tid >> 6;
    const int fr = lane & 15, fk = (lane >> 4) * 8, jr = (lane >> 4) * 4;
    const int ob = blockIdx.x * 64 + w * 16;       // o-base of this wave
    f32x4 acc[4] = {};
    for (int ks = 0; ks < 32; ++ks) {
        s16x8 b = *(const s16x8*)&gwB[(size_t)(ob + fr) * 2048 + 1024 + ks * 32 + fk];
        #pragma unroll
        for (int mt = 0; mt < 4; ++mt) {
            s16x8 a = *(const s16x8*)&memHi[(size_t)(mt * 16 + fr) * HD + ks * 32 + fk];
            acc[mt] = __builtin_amdgcn_mfma_f32_16x16x32_bf16(a, b, acc[mt], 0, 0, 0);
        }
    }
    #pragma unroll
    for (int mt = 0; mt < 4; ++mt)
        #pragma unroll
        for (int j = 0; j < 4; ++j)
            MWmT[(size_t)(ob + fr) * 64 + mt * 16 + jr + j] = f2bf(acc[mt][j]);
}

// ---------------------------------------------------------------------------
// K1: featsB = bf16(x+pos); sim = x*M^T (hi/lo split MFMA) + posM (f32);
//     softmax -> wBg [51200][64] bf16 (zero-padded). Barrier-free;
//     register-prefetch of next panel; 16B stores (8 contiguous cols/thread).
// ---------------------------------------------------------------------------
__global__ __launch_bounds__(256) void k_pre(
    const float* __restrict__ x, const float* __restrict__ pos,
    const u16* __restrict__ memHi, const u16* __restrict__ memLo,
    const float* __restrict__ posM,
    u16* __restrict__ featsB, u16* __restrict__ wBg)
{
    __shared__ u16 fHi[64 * PADK];
    __shared__ u16 fLo[64 * PADK];

    const int tid  = threadIdx.x;
    const int r0   = blockIdx.x * 64;
    const int lane = tid & 63, w = tid >> 6;
    const int fr   = lane & 15;
    const int fk   = (lane >> 4) * 8;
    const int jr   = (lane >> 4) * 4;

    const int srow = tid >> 2;            // 16w..16w+15: wave's own rows
    const int scol = (tid & 3) * 8;       // 8 contiguous cols -> 16B stores
    const int prow = (r0 + srow) % SEQL;

    const float* xrow = &x[(size_t)(r0 + srow) * HD];
    const float* prp  = &pos[(size_t)prow * HD];

    f4 xa[4][2], pa[4][2];
    #pragma unroll
    for (int i = 0; i < 4; ++i) {
        const int c = scol + i * 32;
        xa[i][0] = *(const f4*)&xrow[c];
        xa[i][1] = *(const f4*)&xrow[c + 4];
        pa[i][0] = *(const f4*)&prp[c];
        pa[i][1] = *(const f4*)&prp[c + 4];
    }

    f32x4 acc[4] = {};                    // sim[16 rows][m = n*16 + fr]

    for (int kp = 0; kp < HD; kp += KP) {
        // ---- convert current panel regs -> LDS hi/lo + featsB (16B) ----
        #pragma unroll
        for (int i = 0; i < 4; ++i) {
            const int c = scol + i * 32;
            f4 fa = xa[i][0] + pa[i][0];
            f4 fb = xa[i][1] + pa[i][1];
            u16x8 fv = { f2bf(fa.x), f2bf(fa.y), f2bf(fa.z), f2bf(fa.w),
                         f2bf(fb.x), f2bf(fb.y), f2bf(fb.z), f2bf(fb.w) };
            *(u16x8*)&featsB[(size_t)(r0 + srow) * HD + kp + c] = fv;
            u16x8 hi = { f2bf(xa[i][0].x), f2bf(xa[i][0].y), f2bf(xa[i][0].z), f2bf(xa[i][0].w),
                         f2bf(xa[i][1].x), f2bf(xa[i][1].y), f2bf(xa[i][1].z), f2bf(xa[i][1].w) };
            f4 hv0 = { bf2f(hi[0]), bf2f(hi[1]), bf2f(hi[2]), bf2f(hi[3]) };
            f4 hv1 = { bf2f(hi[4]), bf2f(hi[5]), bf2f(hi[6]), bf2f(hi[7]) };
            f4 l0 = xa[i][0] - hv0, l1 = xa[i][1] - hv1;
            u16x8 lo = { f2bf(l0.x), f2bf(l0.y), f2bf(l0.z), f2bf(l0.w),
                         f2bf(l1.x), f2bf(l1.y), f2bf(l1.z), f2bf(l1.w) };
            *(u16x8*)&fHi[srow * PADK + c] = hi;
            *(u16x8*)&fLo[srow * PADK + c] = lo;
        }
        LGKMFENCE;   // wave-local: LDS writes visible to this wave's reads

        // ---- prefetch next panel into regs (hides HBM under MFMA below) ----
        if (kp + KP < HD) {
            #pragma unroll
            for (int i = 0; i < 4; ++i) {
                const int c = kp + KP + scol + i * 32;
                xa[i][0] = *(const f4*)&xrow[c];
                xa[i][1] = *(const f4*)&xrow[c + 4];
                pa[i][0] = *(const f4*)&prp[c];
                pa[i][1] = *(const f4*)&prp[c + 4];
            }
        }

        // ---- sim MFMA: 3 split-passes, B-frags from L2 (256KB resident) ----
        #pragma unroll
        for (int ks = 0; ks < KP / 32; ++ks) {
            const int kb = ks * 32 + fk;
            s16x8 aH = *(const s16x8*)&fHi[(16 * w + fr) * PADK + kb];
            s16x8 aL = *(const s16x8*)&fLo[(16 * w + fr) * PADK + kb];
            #pragma unroll
            for (int n = 0; n < 4; ++n) {
                const size_t mb = (size_t)(n * 16 + fr) * HD + kp + kb;
                s16x8 bH = *(const s16x8*)&memHi[mb];
                s16x8 bL = *(const s16x8*)&memLo[mb];
                acc[n] = __builtin_amdgcn_mfma_f32_16x16x32_bf16(aH, bH, acc[n], 0, 0, 0);
                acc[n] = __builtin_amdgcn_mfma_f32_16x16x32_bf16(aH, bL, acc[n], 0, 0, 0);
                acc[n] = __builtin_amdgcn_mfma_f32_16x16x32_bf16(aL, bH, acc[n], 0, 0, 0);
            }
        }
        LGKMFENCE;   // panel reads done before next panel's writes
    }

    // softmax over m (50): sim = acc + posM[s][m] (f32)
    #pragma unroll
    for (int j = 0; j < 4; ++j) {
        const int rg = r0 + 16 * w + jr + j;
        const int rr = rg % SEQL;
        float v[4];
        float mx = -1e30f;
        #pragma unroll
        for (int n = 0; n < 4; ++n) {
            v[n] = acc[n][j] + posM[rr * 64 + n * 16 + fr];
            const int m = n * 16 + fr;
            if (m < MEMN) mx = fmaxf(mx, v[n]);
        }
        #pragma unroll
        for (int d = 1; d < 16; d <<= 1) mx = fmaxf(mx, __shfl_xor(mx, d));
        float e[4], s = 0.f;
        #pragma unroll
        for (int n = 0; n < 4; ++n) {
            const int m = n * 16 + fr;
            e[n] = (m < MEMN) ? __expf(v[n] - mx) : 0.f;
            s += e[n];
        }
        #pragma unroll
        for (int d = 1; d < 16; d <<= 1) s += __shfl_xor(s, d);
        const float inv = 1.f / s;
        #pragma unroll
        for (int n = 0; n < 4; ++n)
            wBg[(size_t)rg * 64 + n * 16 + fr] = f2bf(e[n] * inv); // 0 pad m>=50
    }
}

// ---------------------------------------------------------------------------
// K2: out = featsB + sigmoid([featsB|w]@[Wf;MWm] + b) * (w@M).
//     K=1088 (34 tiles). 128x128, BK=32, 4 waves. 3 LDS buffers, clean
//     distance-2 prefetch with <=8 outstanding gload_lds: WAITV4 (tile kt,
//     issued ~2 iters ago) -> barrier -> stage(kt+2) -> ds_read+MFMA -> bar.
//     accR = w@M per-(m,n) in epilogue (no accumulator doubling).
// ---------------------------------------------------------------------------
__global__ __launch_bounds__(256) void k_gate_out(
    const u16* __restrict__ featsB, const u16* __restrict__ wBg,
    const u16* __restrict__ gwB, const u16* __restrict__ memT,
    const u16* __restrict__ MWmT, const float* __restrict__ gb,
    float* __restrict__ out)
{
    __shared__ u16 As[3][128 * 32];   // 24 KB
    __shared__ u16 Bs[3][128 * 32];   // 24 KB

    const int tid = threadIdx.x;
    int bid = blockIdx.x;
    bid = (bid & 7) * 400 + (bid >> 3);      // XCD swizzle (3200 % 8 == 0)
    const int mt = bid >> 3, nt = bid & 7;
    const int row0 = mt * 128, col0 = nt * 128;
    const int lane = tid & 63, wave = tid >> 6;
    const int wr = wave >> 1, wc = wave & 1;
    const int fr = lane & 15, fk = (lane >> 4) * 8;

    f32x4 acc[4][4] = {};

    const int sr = tid >> 2;                 // staging row 0..63
    const int sc = (tid & 3) * 8;            // staging col (elements)

    auto stage = [&](int buf, int kt) {
        if (kt < 32) {
            const int k0 = kt * 32;
            GLOAD_LDS16(featsB + (size_t)(row0 + sr) * HD + k0 + sc,      &As[buf][tid * 8]);
            GLOAD_LDS16(featsB + (size_t)(row0 + 64 + sr) * HD + k0 + sc, &As[buf][2048 + tid * 8]);
            GLOAD_LDS16(gwB + (size_t)(col0 + sr) * 2048 + k0 + sc,      &Bs[buf][tid * 8]);
            GLOAD_LDS16(gwB + (size_t)(col0 + 64 + sr) * 2048 + k0 + sc, &Bs[buf][2048 + tid * 8]);
        } else {
            const int k0 = (kt - 32) * 32;
            GLOAD_LDS16(wBg + (size_t)(row0 + sr) * 64 + k0 + sc,      &As[buf][tid * 8]);
            GLOAD_LDS16(wBg + (size_t)(row0 + 64 + sr) * 64 + k0 + sc, &As[buf][2048 + tid * 8]);
            GLOAD_LDS16(MWmT + (size_t)(col0 + sr) * 64 + k0 + sc,      &Bs[buf][tid * 8]);
            GLOAD_LDS16(MWmT + (size_t)(col0 + 64 + sr) * 64 + k0 + sc, &Bs[buf][2048 + tid * 8]);
        }
    };

    stage(0, 0); stage(1, 1);                // 8 outstanding

    int cur = 0;                             // buffer holding tile kt
    for (int kt = 0; kt < 34; ++kt) {
        if (kt <= 32) { WAITV4; }            // tile kt done (issued ~2 iters ago)
        else          { WAITV0; }
        __builtin_amdgcn_s_barrier();        // tile kt collectively visible
        SCHB;
        if (kt + 2 < 34) {                   // buffer (cur+2)%3 freed at the
            int n2 = cur + 2; if (n2 >= 3) n2 -= 3;   // end-barrier of kt-1
            stage(n2, kt + 2);               // -> 8 outstanding again
        }

        s16x8 aF[4], bF[4];
        #pragma unroll
        for (int m = 0; m < 4; ++m)
            aF[m] = *(const s16x8*)&As[cur][(wr * 64 + m * 16 + fr) * 32 + fk];
        #pragma unroll
        for (int n = 0; n < 4; ++n)
            bF[n] = *(const s16x8*)&Bs[cur][(wc * 64 + n * 16 + fr) * 32 + fk];
        #pragma unroll
        for (int m = 0; m < 4; ++m)
            #pragma unroll
            for (int n = 0; n < 4; ++n)
                acc[m][n] = __builtin_amdgcn_mfma_f32_16x16x32_bf16(
                    aF[m], bF[n], acc[m][n], 0, 0, 0);

        SCHB;
        __builtin_amdgcn_s_barrier();        // all waves done reading cur
        cur = (cur == 2) ? 0 : cur + 1;
    }

    // epilogue: accR = w@M per (m,n); out = feats + sigmoid(acc+b)*accR
    #pragma unroll
    for (int m = 0; m < 4; ++m) {
        const size_t ab = (size_t)(row0 + wr * 64 + m * 16 + fr) * 64 + fk;
        s16x8 a2_0 = *(const s16x8*)&wBg[ab];
        s16x8 a2_1 = *(const s16x8*)&wBg[ab + 32];
        #pragma unroll
        for (int n = 0; n < 4; ++n) {
            const size_t cb = (size_t)(col0 + wc * 64 + n * 16 + fr) * 64 + fk;
            s16x8 bT0 = *(const s16x8*)&memT[cb];
            s16x8 bT1 = *(const s16x8*)&memT[cb + 32];
            f32x4 accR = {};
            accR = __builtin_amdgcn_mfma_f32_16x16x32_bf16(a2_0, bT0, accR, 0, 0, 0);
            accR = __builtin_amdgcn_mfma_f32_16x16x32_bf16(a2_1, bT1, accR, 0, 0, 0);

            const int crow = row0 + wr * 64 + m * 16 + (lane >> 4) * 4;
            const int ccol = col0 + wc * 64 + n * 16 + fr;
            const float bias = gb[ccol];
            #pragma unroll
            for (int j = 0; j < 4; ++j) {
                const size_t idx = (size_t)(crow + j) * HD + ccol;
                const float fe = bf2f(featsB[idx]);
                const float pre = acc[m][n][j] + bias;
                const float g = 1.0f / (1.0f + __expf(-pre));
                out[idx] = fe + g * accR[j];
            }
        }
    }
}

// ---------------------------------------------------------------------------
extern "C" void kernel_launch(void* const* d_in, const int* in_sizes, int n_in,
                              void* d_out, int out_size, void* d_ws, size_t ws_size,
                              hipStream_t stream)
{
    const float* x   = (const float*)d_in[0];
    const float* sm  = (const float*)d_in[1];
    const float* pos = (const float*)d_in[2];
    const float* gw  = (const float*)d_in[3];
    const float* gb  = (const float*)d_in[4];
    float* out = (float*)d_out;

    u16* featsB = (u16*)d_ws;                          // 51200*1024
    u16* gwB    = featsB + (size_t)RTOT * HD;          // 1024*2048
    u16* wBg    = gwB + (size_t)HD * 2048;             // 51200*64
    u16* memHi  = wBg + (size_t)RTOT * 64;             // 64*1024
    u16* memLo  = memHi + 64 * HD;                     // 64*1024
    u16* memT   = memLo + 64 * HD;                     // 1024*64
    u16* MWmT   = memT + (size_t)HD * 64;              // 1024*64
    float* posM = (float*)(MWmT + (size_t)HD * 64);    // 200*64 f32

    k_cvt_w<<<dim3(1024), dim3(256), 0, stream>>>(gw, gwB);
    k_prep_mem<<<dim3(64), dim3(256), 0, stream>>>(sm, memHi, memLo, memT);
    k_posm<<<dim3(SEQL), dim3(256), 0, stream>>>(pos, sm, posM);
    k_mwm<<<dim3(16), dim3(256), 0, stream>>>(memHi, gwB, MWmT);
    k_pre<<<dim3(RTOT / 64), dim3(256), 0, stream>>>(x, pos, memHi, memLo, posM,
                                                     featsB, wBg);
    k_gate_out<<<dim3(3200), dim3(256), 0, stream>>>(featsB, wBg, gwB, memT,
                                                     MWmT, gb, out);
}

// Round 10
// 441.816 us; speedup vs baseline: 1.5953x; 1.0726x over previous
//
#include <hip/hip_runtime.h>
#include <cstdint>
#include <cstddef>

#define HD   1024
#define SEQL 200
#define MEMN 50
#define RTOT 51200   // 256 * 200
#define KP   128
#define PADK 136     // KP + 8 bf16 pad -> LDS row stride 272B (2-way, free)

typedef float  f4    __attribute__((ext_vector_type(4)));
typedef float  f32x4 __attribute__((ext_vector_type(4)));
typedef short  s16x8 __attribute__((ext_vector_type(8)));
typedef unsigned short u16;
typedef unsigned short u16x4 __attribute__((ext_vector_type(4)));
typedef unsigned short u16x8 __attribute__((ext_vector_type(8)));

__device__ __forceinline__ u16 f2bf(float f) {
    unsigned u = __builtin_bit_cast(unsigned, f);
    u += 0x7FFFu + ((u >> 16) & 1u);          // RNE
    return (u16)(u >> 16);
}
__device__ __forceinline__ float bf2f(u16 h) {
    unsigned u = ((unsigned)h) << 16;
    return __builtin_bit_cast(float, u);
}

#define GLOAD_LDS16(g, l) __builtin_amdgcn_global_load_lds( \
    (const __attribute__((address_space(1))) unsigned int*)(g), \
    (__attribute__((address_space(3))) unsigned int*)(l), 16, 0, 0)

#define WAITV3 asm volatile("s_waitcnt vmcnt(3)" ::: "memory")
#define WAITV0 asm volatile("s_waitcnt vmcnt(0)" ::: "memory")
#define LGKMFENCE asm volatile("s_waitcnt lgkmcnt(0)" ::: "memory")
#define SCHB   __builtin_amdgcn_sched_barrier(0)

// ---------------------------------------------------------------------------
// K0a: gate_w f32 -> bf16, layout [o][2048] k-contig. Wf = cols 0..1023,
//      Wm = cols 1024..2047.
// ---------------------------------------------------------------------------
__global__ __launch_bounds__(256) void k_cvt_w(const float* __restrict__ gw,
                                               u16* __restrict__ gwB)
{
    const size_t i = ((size_t)blockIdx.x * 256 + threadIdx.x) * 8;
    f4 v0 = *(const f4*)&gw[i];
    f4 v1 = *(const f4*)&gw[i + 4];
    u16x4 b0 = { f2bf(v0.x), f2bf(v0.y), f2bf(v0.z), f2bf(v0.w) };
    u16x4 b1 = { f2bf(v1.x), f2bf(v1.y), f2bf(v1.z), f2bf(v1.w) };
    *(u16x4*)&gwB[i]     = b0;
    *(u16x4*)&gwB[i + 4] = b1;
}

// ---------------------------------------------------------------------------
// K0b: spatial memory -> {memHi, memLo} [64][1024] bf16 (rows 50..63 zero)
//      and memT [1024][64] bf16 (hi, transposed, zero-padded).
// ---------------------------------------------------------------------------
__global__ __launch_bounds__(256) void k_prep_mem(const float* __restrict__ sm,
                                                  u16* __restrict__ memHi,
                                                  u16* __restrict__ memLo,
                                                  u16* __restrict__ memT)
{
    const int idx = blockIdx.x * 256 + threadIdx.x;   // 16384 total
    const int m  = idx >> 8;
    const int h0 = (idx & 255) * 4;
    f4 v = {0.f, 0.f, 0.f, 0.f};
    if (m < MEMN) v = *(const f4*)&sm[(size_t)m * HD + h0];
    u16x4 hi = { f2bf(v.x), f2bf(v.y), f2bf(v.z), f2bf(v.w) };
    f4 hv = { bf2f(hi.x), bf2f(hi.y), bf2f(hi.z), bf2f(hi.w) };
    f4 lv = v - hv;
    u16x4 lo = { f2bf(lv.x), f2bf(lv.y), f2bf(lv.z), f2bf(lv.w) };
    *(u16x4*)&memHi[(size_t)m * HD + h0] = hi;
    *(u16x4*)&memLo[(size_t)m * HD + h0] = lo;
    memT[(size_t)(h0 + 0) * 64 + m] = hi.x;
    memT[(size_t)(h0 + 1) * 64 + m] = hi.y;
    memT[(size_t)(h0 + 2) * 64 + m] = hi.z;
    memT[(size_t)(h0 + 3) * 64 + m] = hi.w;
}

// ---------------------------------------------------------------------------
// K0d: MWmT[o][m] = (M @ Wm)(m,o) as bf16, [1024][64].  MFMA, 16 blocks.
// ---------------------------------------------------------------------------
__global__ __launch_bounds__(256) void k_mwm(const u16* __restrict__ memHi,
                                             const u16* __restrict__ gwB,
                                             u16* __restrict__ MWmT)
{
    const int tid = threadIdx.x, lane = tid & 63, w = tid >> 6;
    const int fr = lane & 15, fk = (lane >> 4) * 8, jr = (lane >> 4) * 4;
    const int ob = blockIdx.x * 64 + w * 16;       // o-base of this wave
    f32x4 acc[4] = {};
    for (int ks = 0; ks < 32; ++ks) {
        s16x8 b = *(const s16x8*)&gwB[(size_t)(ob + fr) * 2048 + 1024 + ks * 32 + fk];
        #pragma unroll
        for (int mt = 0; mt < 4; ++mt) {
            s16x8 a = *(const s16x8*)&memHi[(size_t)(mt * 16 + fr) * HD + ks * 32 + fk];
            acc[mt] = __builtin_amdgcn_mfma_f32_16x16x32_bf16(a, b, acc[mt], 0, 0, 0);
        }
    }
    #pragma unroll
    for (int mt = 0; mt < 4; ++mt)
        #pragma unroll
        for (int j = 0; j < 4; ++j)
            MWmT[(size_t)(ob + fr) * 64 + mt * 16 + jr + j] = f2bf(acc[mt][j]);
}

// ---------------------------------------------------------------------------
// K1: feats = x + pos (f32); featsB = bf16(feats) = hi; lo = bf16(feats-hi);
//     sim = feats(hi/lo) @ M(hi/lo)^T, 3 split-pass MFMA (lo*lo dropped);
//     softmax -> wBg [51200][64] bf16 (zero-padded). Barrier-free;
//     register-prefetch of next panel; 16B stores.
// ---------------------------------------------------------------------------
__global__ __launch_bounds__(256) void k_pre(
    const float* __restrict__ x, const float* __restrict__ pos,
    const u16* __restrict__ memHi, const u16* __restrict__ memLo,
    u16* __restrict__ featsB, u16* __restrict__ wBg)
{
    __shared__ u16 fHi[64 * PADK];
    __shared__ u16 fLo[64 * PADK];

    const int tid  = threadIdx.x;
    const int r0   = blockIdx.x * 64;
    const int lane = tid & 63, w = tid >> 6;
    const int fr   = lane & 15;
    const int fk   = (lane >> 4) * 8;
    const int jr   = (lane >> 4) * 4;

    const int srow = tid >> 2;            // 16w..16w+15: wave's own rows
    const int scol = (tid & 3) * 8;       // 8 contiguous cols -> 16B stores
    const int prow = (r0 + srow) % SEQL;

    const float* xrow = &x[(size_t)(r0 + srow) * HD];
    const float* prp  = &pos[(size_t)prow * HD];

    f4 xa[4][2], pa[4][2];
    #pragma unroll
    for (int i = 0; i < 4; ++i) {
        const int c = scol + i * 32;
        xa[i][0] = *(const f4*)&xrow[c];
        xa[i][1] = *(const f4*)&xrow[c + 4];
        pa[i][0] = *(const f4*)&prp[c];
        pa[i][1] = *(const f4*)&prp[c + 4];
    }

    f32x4 acc[4] = {};                    // sim[16 rows][m = n*16 + fr]

    for (int kp = 0; kp < HD; kp += KP) {
        // ---- convert current panel regs -> LDS hi/lo + featsB (16B) ----
        #pragma unroll
        for (int i = 0; i < 4; ++i) {
            const int c = scol + i * 32;
            f4 fa = xa[i][0] + pa[i][0];
            f4 fb = xa[i][1] + pa[i][1];
            u16x8 hi = { f2bf(fa.x), f2bf(fa.y), f2bf(fa.z), f2bf(fa.w),
                         f2bf(fb.x), f2bf(fb.y), f2bf(fb.z), f2bf(fb.w) };
            *(u16x8*)&featsB[(size_t)(r0 + srow) * HD + kp + c] = hi;
            f4 hv0 = { bf2f(hi[0]), bf2f(hi[1]), bf2f(hi[2]), bf2f(hi[3]) };
            f4 hv1 = { bf2f(hi[4]), bf2f(hi[5]), bf2f(hi[6]), bf2f(hi[7]) };
            f4 l0 = fa - hv0, l1 = fb - hv1;
            u16x8 lo = { f2bf(l0.x), f2bf(l0.y), f2bf(l0.z), f2bf(l0.w),
                         f2bf(l1.x), f2bf(l1.y), f2bf(l1.z), f2bf(l1.w) };
            *(u16x8*)&fHi[srow * PADK + c] = hi;
            *(u16x8*)&fLo[srow * PADK + c] = lo;
        }
        LGKMFENCE;   // wave-local: LDS writes visible to this wave's reads

        // ---- prefetch next panel into regs (hides HBM under MFMA below) ----
        if (kp + KP < HD) {
            #pragma unroll
            for (int i = 0; i < 4; ++i) {
                const int c = kp + KP + scol + i * 32;
                xa[i][0] = *(const f4*)&xrow[c];
                xa[i][1] = *(const f4*)&xrow[c + 4];
                pa[i][0] = *(const f4*)&prp[c];
                pa[i][1] = *(const f4*)&prp[c + 4];
            }
        }

        // ---- sim MFMA: 3 split-passes, B-frags from L2 (256KB resident) ----
        #pragma unroll
        for (int ks = 0; ks < KP / 32; ++ks) {
            const int kb = ks * 32 + fk;
            s16x8 aH = *(const s16x8*)&fHi[(16 * w + fr) * PADK + kb];
            s16x8 aL = *(const s16x8*)&fLo[(16 * w + fr) * PADK + kb];
            #pragma unroll
            for (int n = 0; n < 4; ++n) {
                const size_t mb = (size_t)(n * 16 + fr) * HD + kp + kb;
                s16x8 bH = *(const s16x8*)&memHi[mb];
                s16x8 bL = *(const s16x8*)&memLo[mb];
                acc[n] = __builtin_amdgcn_mfma_f32_16x16x32_bf16(aH, bH, acc[n], 0, 0, 0);
                acc[n] = __builtin_amdgcn_mfma_f32_16x16x32_bf16(aH, bL, acc[n], 0, 0, 0);
                acc[n] = __builtin_amdgcn_mfma_f32_16x16x32_bf16(aL, bH, acc[n], 0, 0, 0);
            }
        }
        LGKMFENCE;   // panel reads done before next panel's writes
    }

    // softmax over m (50)
    #pragma unroll
    for (int j = 0; j < 4; ++j) {
        const int rg = r0 + 16 * w + jr + j;
        float v[4];
        float mx = -1e30f;
        #pragma unroll
        for (int n = 0; n < 4; ++n) {
            v[n] = acc[n][j];
            const int m = n * 16 + fr;
            if (m < MEMN) mx = fmaxf(mx, v[n]);
        }
        #pragma unroll
        for (int d = 1; d < 16; d <<= 1) mx = fmaxf(mx, __shfl_xor(mx, d));
        float e[4], s = 0.f;
        #pragma unroll
        for (int n = 0; n < 4; ++n) {
            const int m = n * 16 + fr;
            e[n] = (m < MEMN) ? __expf(v[n] - mx) : 0.f;
            s += e[n];
        }
        #pragma unroll
        for (int d = 1; d < 16; d <<= 1) s += __shfl_xor(s, d);
        const float inv = 1.f / s;
        #pragma unroll
        for (int n = 0; n < 4; ++n)
            wBg[(size_t)rg * 64 + n * 16 + fr] = f2bf(e[n] * inv); // 0 pad m>=50
    }
}

// ---------------------------------------------------------------------------
// K2: out = featsB + sigmoid([featsB|w]@[Wf;MWm] + b) * (w@M).
//     K=1088 (34 tiles). BM=256, BN=128, BK=32, 8 waves (4Mx2N, 512 thr).
//     2 LDS buffers dist-1 (48 KB -> 3 blocks/CU = 24 waves/CU), vmcnt(3).
//     Barrier cost per FLOP halved vs 128x128. accR = w@M in epilogue.
// ---------------------------------------------------------------------------
__global__ __launch_bounds__(512) void k_gate_out(
    const u16* __restrict__ featsB, const u16* __restrict__ wBg,
    const u16* __restrict__ gwB, const u16* __restrict__ memT,
    const u16* __restrict__ MWmT, const float* __restrict__ gb,
    float* __restrict__ out)
{
    __shared__ u16 As[2][256 * 32];   // 2 x 16 KB
    __shared__ u16 Bs[2][128 * 32];   // 2 x 8 KB

    const int tid = threadIdx.x;
    int bid = blockIdx.x;
    bid = (bid & 7) * 200 + (bid >> 3);      // XCD swizzle (1600 % 8 == 0)
    const int mt = bid >> 3, nt = bid & 7;   // 200 x 8 tiles
    const int row0 = mt * 256, col0 = nt * 128;
    const int lane = tid & 63, wave = tid >> 6;
    const int wm = wave >> 1, wn = wave & 1; // 4M x 2N (64x64 each)
    const int fr = lane & 15, fk = (lane >> 4) * 8;

    f32x4 acc[4][4] = {};

    const int sr = tid >> 2;                 // staging row 0..127
    const int sc = (tid & 3) * 8;            // staging col (elements)

    auto stage = [&](int buf, int kt) {
        if (kt < 32) {
            const int k0 = kt * 32;
            GLOAD_LDS16(featsB + (size_t)(row0 + sr) * HD + k0 + sc,       &As[buf][tid * 8]);
            GLOAD_LDS16(featsB + (size_t)(row0 + 128 + sr) * HD + k0 + sc, &As[buf][4096 + tid * 8]);
            GLOAD_LDS16(gwB + (size_t)(col0 + sr) * 2048 + k0 + sc,        &Bs[buf][tid * 8]);
        } else {
            const int k0 = (kt - 32) * 32;
            GLOAD_LDS16(wBg + (size_t)(row0 + sr) * 64 + k0 + sc,          &As[buf][tid * 8]);
            GLOAD_LDS16(wBg + (size_t)(row0 + 128 + sr) * 64 + k0 + sc,    &As[buf][4096 + tid * 8]);
            GLOAD_LDS16(MWmT + (size_t)(col0 + sr) * 64 + k0 + sc,         &Bs[buf][tid * 8]);
        }
    };

    stage(0, 0);
    int cur = 0;

    for (int kt = 0; kt < 34; ++kt) {
        if (kt < 33) {
            stage(cur ^ 1, kt + 1);
            WAITV3;                          // cur's 3 loads done
        } else {
            WAITV0;
        }
        __builtin_amdgcn_s_barrier();
        SCHB;

        s16x8 aF[4], bF[4];
        #pragma unroll
        for (int m = 0; m < 4; ++m)
            aF[m] = *(const s16x8*)&As[cur][(wm * 64 + m * 16 + fr) * 32 + fk];
        #pragma unroll
        for (int n = 0; n < 4; ++n)
            bF[n] = *(const s16x8*)&Bs[cur][(wn * 64 + n * 16 + fr) * 32 + fk];
        #pragma unroll
        for (int m = 0; m < 4; ++m)
            #pragma unroll
            for (int n = 0; n < 4; ++n)
                acc[m][n] = __builtin_amdgcn_mfma_f32_16x16x32_bf16(
                    aF[m], bF[n], acc[m][n], 0, 0, 0);

        SCHB;
        __builtin_amdgcn_s_barrier();
        cur ^= 1;
    }

    // epilogue: accR = w@M per (m,n); out = feats + sigmoid(acc+b)*accR
    #pragma unroll
    for (int m = 0; m < 4; ++m) {
        const size_t ab = (size_t)(row0 + wm * 64 + m * 16 + fr) * 64 + fk;
        s16x8 a2_0 = *(const s16x8*)&wBg[ab];
        s16x8 a2_1 = *(const s16x8*)&wBg[ab + 32];
        #pragma unroll
        for (int n = 0; n < 4; ++n) {
            const size_t cb = (size_t)(col0 + wn * 64 + n * 16 + fr) * 64 + fk;
            s16x8 bT0 = *(const s16x8*)&memT[cb];
            s16x8 bT1 = *(const s16x8*)&memT[cb + 32];
            f32x4 accR = {};
            accR = __builtin_amdgcn_mfma_f32_16x16x32_bf16(a2_0, bT0, accR, 0, 0, 0);
            accR = __builtin_amdgcn_mfma_f32_16x16x32_bf16(a2_1, bT1, accR, 0, 0, 0);

            const int crow = row0 + wm * 64 + m * 16 + (lane >> 4) * 4;
            const int ccol = col0 + wn * 64 + n * 16 + fr;
            const float bias = gb[ccol];
            #pragma unroll
            for (int j = 0; j < 4; ++j) {
                const size_t idx = (size_t)(crow + j) * HD + ccol;
                const float fe = bf2f(featsB[idx]);
                const float pre = acc[m][n][j] + bias;
                const float g = 1.0f / (1.0f + __expf(-pre));
                out[idx] = fe + g * accR[j];
            }
        }
    }
}

// ---------------------------------------------------------------------------
extern "C" void kernel_launch(void* const* d_in, const int* in_sizes, int n_in,
                              void* d_out, int out_size, void* d_ws, size_t ws_size,
                              hipStream_t stream)
{
    const float* x   = (const float*)d_in[0];
    const float* sm  = (const float*)d_in[1];
    const float* pos = (const float*)d_in[2];
    const float* gw  = (const float*)d_in[3];
    const float* gb  = (const float*)d_in[4];
    float* out = (float*)d_out;

    u16* featsB = (u16*)d_ws;                          // 51200*1024
    u16* gwB    = featsB + (size_t)RTOT * HD;          // 1024*2048
    u16* wBg    = gwB + (size_t)HD * 2048;             // 51200*64
    u16* memHi  = wBg + (size_t)RTOT * 64;             // 64*1024
    u16* memLo  = memHi + 64 * HD;                     // 64*1024
    u16* memT   = memLo + 64 * HD;                     // 1024*64
    u16* MWmT   = memT + (size_t)HD * 64;              // 1024*64

    k_cvt_w<<<dim3(1024), dim3(256), 0, stream>>>(gw, gwB);
    k_prep_mem<<<dim3(64), dim3(256), 0, stream>>>(sm, memHi, memLo, memT);
    k_mwm<<<dim3(16), dim3(256), 0, stream>>>(memHi, gwB, MWmT);
    k_pre<<<dim3(RTOT / 64), dim3(256), 0, stream>>>(x, pos, memHi, memLo,
                                                     featsB, wBg);
    k_gate_out<<<dim3(1600), dim3(512), 0, stream>>>(featsB, wBg, gwB, memT,
                                                     MWmT, gb, out);
}